// Round 1
// baseline (932.252 us; speedup 1.0000x reference)
//
#include <hip/hip_runtime.h>
#include <math.h>

// Problem constants (from reference): B,S,N,H,C
constexpr int B_ = 32, S_ = 128, N_ = 1024, H_ = 2, C_ = 128;
#define NEG_SLOPE_ 0.2f

__device__ __forceinline__ float lrelu(float v) {
    return v >= 0.f ? v : NEG_SLOPE_ * v;
}

// -----------------------------------------------------------------------------
// Kernel 1: z[b,h,n,c] = sum_s x[b,s,n] * W[h,s,c]
//           ssrc[b,h,n] = z . att_src[h], sdst likewise.
// Block: 256 threads, tile 64n x 128c, K=S=128 in 4 chunks of 32.
// Thread (ty,tx): n = nb + ty*4 + r (r<4), c = tx*8 + j (j<8) -> 4x8 acc.
// -----------------------------------------------------------------------------
__global__ __launch_bounds__(256)
void proj_kernel(const float* __restrict__ x, const float* __restrict__ W,
                 const float* __restrict__ att_src, const float* __restrict__ att_dst,
                 float* __restrict__ z, float* __restrict__ ssrc,
                 float* __restrict__ sdst)
{
    const int nb = blockIdx.x * 64;
    const int bh = blockIdx.y;           // b*H + h
    const int b  = bh >> 1, h = bh & 1;
    const int tid = threadIdx.x;
    const int tx = tid & 15, ty = tid >> 4;

    __shared__ float xs[32][64];     // [k][n]
    __shared__ float wsh[32][128];   // [k][c]

    float acc[4][8];
#pragma unroll
    for (int r = 0; r < 4; ++r)
#pragma unroll
        for (int j = 0; j < 8; ++j) acc[r][j] = 0.f;

    const float* xb = x + (size_t)b * S_ * N_;
    const float* Wh = W + (size_t)h * S_ * C_;

    for (int k0 = 0; k0 < S_; k0 += 32) {
        // stage x chunk: 32k x 64n, coalesced over n
#pragma unroll
        for (int i = 0; i < 8; ++i) {
            int e = tid + i * 256;
            int kk = e >> 6, nn = e & 63;
            xs[kk][nn] = xb[(size_t)(k0 + kk) * N_ + nb + nn];
        }
        // stage W chunk: 32k x 128c, coalesced over c
#pragma unroll
        for (int i = 0; i < 16; ++i) {
            int e = tid + i * 256;
            int kk = e >> 7, cc = e & 127;
            wsh[kk][cc] = Wh[(k0 + kk) * C_ + cc];
        }
        __syncthreads();
#pragma unroll
        for (int k = 0; k < 32; ++k) {
            float a[4], bb[8];
#pragma unroll
            for (int r = 0; r < 4; ++r) a[r] = xs[k][ty * 4 + r];
#pragma unroll
            for (int j = 0; j < 8; ++j) bb[j] = wsh[k][tx * 8 + j];
#pragma unroll
            for (int r = 0; r < 4; ++r)
#pragma unroll
                for (int j = 0; j < 8; ++j)
                    acc[r][j] = fmaf(a[r], bb[j], acc[r][j]);
        }
        __syncthreads();
    }

    // write z (c-contiguous, float4 x2 per row)
    float* zrow = z + ((size_t)bh * N_ + nb) * C_;
#pragma unroll
    for (int r = 0; r < 4; ++r) {
        float4* p = (float4*)(zrow + (size_t)(ty * 4 + r) * C_ + tx * 8);
        p[0] = make_float4(acc[r][0], acc[r][1], acc[r][2], acc[r][3]);
        p[1] = make_float4(acc[r][4], acc[r][5], acc[r][6], acc[r][7]);
    }

    // fused score dots: s[n] = sum_c z[n,c]*att[c]; reduce over tx (16 lanes)
    float asrc[8], adst[8];
#pragma unroll
    for (int j = 0; j < 8; ++j) {
        asrc[j] = att_src[h * C_ + tx * 8 + j];
        adst[j] = att_dst[h * C_ + tx * 8 + j];
    }
#pragma unroll
    for (int r = 0; r < 4; ++r) {
        float ps = 0.f, pd = 0.f;
#pragma unroll
        for (int j = 0; j < 8; ++j) {
            ps = fmaf(acc[r][j], asrc[j], ps);
            pd = fmaf(acc[r][j], adst[j], pd);
        }
#pragma unroll
        for (int msk = 8; msk >= 1; msk >>= 1) {
            ps += __shfl_xor(ps, msk, 64);
            pd += __shfl_xor(pd, msk, 64);
        }
        if (tx == 0) {
            ssrc[(size_t)bh * N_ + nb + ty * 4 + r] = ps;
            sdst[(size_t)bh * N_ + nb + ty * 4 + r] = pd;
        }
    }
}

// -----------------------------------------------------------------------------
// Kernel 2: out[b,c,i] = bias[c] + (1/H) * sum_h sum_j alpha[i,j] * z[b,h,j,c]
//           alpha = softmax_j( lrelu(sdst[i] + ssrc[j]) )
// Block: 256 threads, tile 64i x 128c, j in chunks of 32, 2-pass softmax.
// -----------------------------------------------------------------------------
__global__ __launch_bounds__(256)
void attn_kernel(const float* __restrict__ z, const float* __restrict__ ssrc,
                 const float* __restrict__ sdst, const float* __restrict__ bias,
                 float* __restrict__ out)
{
    const int ib = blockIdx.x * 64;
    const int b  = blockIdx.y;
    const int tid = threadIdx.x;
    const int tx = tid & 15, ty = tid >> 4;

    __shared__ float ssj[N_];         // all source scores (4 KB)
    __shared__ float alpha[32][68];   // [j][i] transposed, padded (8.5 KB)
    __shared__ float zs[32][128];     // z chunk [j][c] (16 KB)
    __shared__ float obuf[128][64];   // output transpose buffer (32 KB)

    float acc[4][8];
#pragma unroll
    for (int r = 0; r < 4; ++r)
#pragma unroll
        for (int j = 0; j < 8; ++j) acc[r][j] = 0.f;

    for (int h = 0; h < H_; ++h) {
        __syncthreads();  // prior head's LDS consumers done before ssj overwrite
        const size_t bh = (size_t)(b * H_ + h);
        const float* zh = z + bh * N_ * C_;
        const float* ss = ssrc + bh * N_;
        for (int i = tid; i < N_; i += 256) ssj[i] = ss[i];
        __syncthreads();

        float d[4];
#pragma unroll
        for (int r = 0; r < 4; ++r) d[r] = sdst[bh * N_ + ib + ty * 4 + r];

        // pass 1: online (m,l) per row; each row scanned by its 16-lane group
        float m[4], l[4];
#pragma unroll
        for (int r = 0; r < 4; ++r) { m[r] = -1e30f; l[r] = 0.f; }
        for (int j = tx; j < N_; j += 16) {
            float sj = ssj[j];
#pragma unroll
            for (int r = 0; r < 4; ++r) {
                float e = lrelu(d[r] + sj);
                float nm = fmaxf(m[r], e);
                l[r] = l[r] * __expf(m[r] - nm) + __expf(e - nm);
                m[r] = nm;
            }
        }
        // butterfly combine across the 16-lane group
#pragma unroll
        for (int msk = 1; msk < 16; msk <<= 1) {
#pragma unroll
            for (int r = 0; r < 4; ++r) {
                float om = __shfl_xor(m[r], msk, 64);
                float ol = __shfl_xor(l[r], msk, 64);
                float nm = fmaxf(m[r], om);
                l[r] = l[r] * __expf(m[r] - nm) + ol * __expf(om - nm);
                m[r] = nm;
            }
        }
        float il[4];
#pragma unroll
        for (int r = 0; r < 4; ++r) il[r] = 1.f / l[r];

        // pass 2: accumulate normalized alpha @ z over j chunks of 32
        for (int j0 = 0; j0 < N_; j0 += 32) {
            __syncthreads();  // previous chunk consumers done
            // fill alpha[j][i] (each thread: 2 j x its 4 rows)
#pragma unroll
            for (int jj = 0; jj < 2; ++jj) {
                int jl = tx * 2 + jj;
                float sj = ssj[j0 + jl];
#pragma unroll
                for (int r = 0; r < 4; ++r) {
                    float e = lrelu(d[r] + sj);
                    alpha[jl][ty * 4 + r] = __expf(e - m[r]) * il[r];
                }
            }
            // stage z chunk 32j x 128c, coalesced over c
#pragma unroll
            for (int i = 0; i < 16; ++i) {
                int e2 = tid + i * 256;
                int kk = e2 >> 7, cc = e2 & 127;
                zs[kk][cc] = zh[(size_t)(j0 + kk) * C_ + cc];
            }
            __syncthreads();
#pragma unroll
            for (int k = 0; k < 32; ++k) {
                float a[4], bb[8];
#pragma unroll
                for (int r = 0; r < 4; ++r) a[r] = alpha[k][ty * 4 + r];
#pragma unroll
                for (int j = 0; j < 8; ++j) bb[j] = zs[k][tx * 8 + j];
#pragma unroll
                for (int r = 0; r < 4; ++r)
#pragma unroll
                    for (int j = 0; j < 8; ++j)
                        acc[r][j] = fmaf(a[r], bb[j], acc[r][j]);
            }
        }
    }

    __syncthreads();
    // stage head-mean to obuf[c][i] for coalesced transposed write
#pragma unroll
    for (int r = 0; r < 4; ++r)
#pragma unroll
        for (int j = 0; j < 8; ++j)
            obuf[tx * 8 + j][ty * 4 + r] = acc[r][j] * 0.5f;
    __syncthreads();

    {
        int c = tid >> 1;
        int i0 = (tid & 1) * 32;
        float bv = bias[c];
        float* op = out + ((size_t)b * C_ + c) * N_ + ib + i0;
#pragma unroll
        for (int t = 0; t < 8; ++t) {
            float4 v;
            v.x = obuf[c][i0 + t * 4 + 0] + bv;
            v.y = obuf[c][i0 + t * 4 + 1] + bv;
            v.z = obuf[c][i0 + t * 4 + 2] + bv;
            v.w = obuf[c][i0 + t * 4 + 3] + bv;
            ((float4*)op)[t] = v;
        }
    }
}

extern "C" void kernel_launch(void* const* d_in, const int* in_sizes, int n_in,
                              void* d_out, int out_size, void* d_ws, size_t ws_size,
                              hipStream_t stream) {
    const float* x       = (const float*)d_in[0];
    const float* W       = (const float*)d_in[1];
    const float* att_src = (const float*)d_in[2];
    const float* att_dst = (const float*)d_in[3];
    const float* bias    = (const float*)d_in[4];
    float* out = (float*)d_out;

    // workspace layout: z [B,H,N,C] fp32, ssrc [B,H,N], sdst [B,H,N] = ~34.1 MB
    float* z    = (float*)d_ws;
    float* ssrc = z + (size_t)B_ * H_ * N_ * C_;
    float* sdst = ssrc + (size_t)B_ * H_ * N_;

    proj_kernel<<<dim3(N_ / 64, B_ * H_), 256, 0, stream>>>(
        x, W, att_src, att_dst, z, ssrc, sdst);
    attn_kernel<<<dim3(N_ / 64, B_), 256, 0, stream>>>(
        z, ssrc, sdst, bias, out);
}

// Round 2
// 218.498 us; speedup vs baseline: 4.2666x; 4.2666x over previous
//
#include <hip/hip_runtime.h>
#include <hip/hip_bf16.h>
#include <math.h>

// Problem constants (from reference): B,S,N,H,C
constexpr int B_ = 32, S_ = 128, N_ = 1024, H_ = 2, C_ = 128;
#define L2E_ 1.44269504088896340736f

typedef short bf16x8 __attribute__((ext_vector_type(8)));
typedef float f32x4  __attribute__((ext_vector_type(4)));

__device__ __forceinline__ ushort f2bf(float f) {
    __hip_bfloat16 h = __float2bfloat16(f);
    return __builtin_bit_cast(ushort, h);
}

// -----------------------------------------------------------------------------
// Kernel 1: z[b,h,n,c] = sum_s x[b,s,n] * W[h,s,c]  (fp32 accumulate)
//   writes zT[bh][c][n] as bf16 (transposed via LDS, XOR-swizzled buffer)
//   ssrc[b,h,n] = z . att_src[h], sdst likewise (fp32, from fp32 acc).
// Block: 256 threads, tile 64n x 128c. Thread (ty,tx): n=ty*4+r, c=tx*8+j.
// -----------------------------------------------------------------------------
__global__ __launch_bounds__(256)
void proj_kernel(const float* __restrict__ x, const float* __restrict__ W,
                 const float* __restrict__ att_src, const float* __restrict__ att_dst,
                 ushort* __restrict__ zt, float* __restrict__ ssrc,
                 float* __restrict__ sdst)
{
    const int nb = blockIdx.x * 64;
    const int bh = blockIdx.y;           // b*H + h
    const int b  = bh >> 1, h = bh & 1;
    const int tid = threadIdx.x;
    const int tx = tid & 15, ty = tid >> 4;

    __shared__ float smem[32 * 64 + 32 * 128];   // xs [32][64] | wsh [32][128]
    float* xs  = smem;            // [k][n]
    float* wsh = smem + 32 * 64;  // [k][c]

    float acc[4][8];
#pragma unroll
    for (int r = 0; r < 4; ++r)
#pragma unroll
        for (int j = 0; j < 8; ++j) acc[r][j] = 0.f;

    const float* xb = x + (size_t)b * S_ * N_;
    const float* Wh = W + (size_t)h * S_ * C_;

    for (int k0 = 0; k0 < S_; k0 += 32) {
#pragma unroll
        for (int i = 0; i < 8; ++i) {
            int e = tid + i * 256;
            int kk = e >> 6, nn = e & 63;
            xs[kk * 64 + nn] = xb[(size_t)(k0 + kk) * N_ + nb + nn];
        }
#pragma unroll
        for (int i = 0; i < 16; ++i) {
            int e = tid + i * 256;
            int kk = e >> 7, cc = e & 127;
            wsh[kk * 128 + cc] = Wh[(k0 + kk) * C_ + cc];
        }
        __syncthreads();
#pragma unroll
        for (int k = 0; k < 32; ++k) {
            float a[4], bb[8];
#pragma unroll
            for (int r = 0; r < 4; ++r) a[r] = xs[k * 64 + ty * 4 + r];
#pragma unroll
            for (int j = 0; j < 8; ++j) bb[j] = wsh[k * 128 + tx * 8 + j];
#pragma unroll
            for (int r = 0; r < 4; ++r)
#pragma unroll
                for (int j = 0; j < 8; ++j)
                    acc[r][j] = fmaf(a[r], bb[j], acc[r][j]);
        }
        __syncthreads();
    }

    // fused score dots (fp32, exact): s[n] = sum_c z[n,c]*att[c]
    float asrc[8], adst[8];
#pragma unroll
    for (int j = 0; j < 8; ++j) {
        asrc[j] = att_src[h * C_ + tx * 8 + j];
        adst[j] = att_dst[h * C_ + tx * 8 + j];
    }
#pragma unroll
    for (int r = 0; r < 4; ++r) {
        float ps = 0.f, pd = 0.f;
#pragma unroll
        for (int j = 0; j < 8; ++j) {
            ps = fmaf(acc[r][j], asrc[j], ps);
            pd = fmaf(acc[r][j], adst[j], pd);
        }
#pragma unroll
        for (int msk = 8; msk >= 1; msk >>= 1) {
            ps += __shfl_xor(ps, msk, 64);
            pd += __shfl_xor(pd, msk, 64);
        }
        if (tx == 0) {
            ssrc[(size_t)bh * N_ + nb + ty * 4 + r] = ps;
            sdst[(size_t)bh * N_ + nb + ty * 4 + r] = pd;
        }
    }

    // transpose z tile to bf16 via LDS (reuses smem; all k-loop reads done).
    // zbuf[c][nloc] ushort, XOR-swizzled by bits 3..5 of c to spread banks.
    ushort* zbuf = (ushort*)smem;   // 128*64 ushorts = 16 KB
#pragma unroll
    for (int j = 0; j < 8; ++j) {
        int c  = tx * 8 + j;
        int sw = ((c >> 3) & 7) * 8;
        ushort4 v;
        v.x = f2bf(acc[0][j]); v.y = f2bf(acc[1][j]);
        v.z = f2bf(acc[2][j]); v.w = f2bf(acc[3][j]);
        *(ushort4*)&zbuf[c * 64 + ((ty * 4) ^ sw)] = v;
    }
    __syncthreads();

    const size_t ztbase = (size_t)bh * ((size_t)C_ * N_);
#pragma unroll
    for (int it = 0; it < 8; ++it) {
        int id = it * 256 + tid;
        int c = id >> 4, c2 = id & 15;
        int sw = ((c >> 3) & 7) * 8;
        ushort4 v = *(const ushort4*)&zbuf[c * 64 + ((c2 * 4) ^ sw)];
        *(ushort4*)&zt[ztbase + (size_t)c * N_ + nb + c2 * 4] = v;
    }
}

// -----------------------------------------------------------------------------
// Kernel 2 (MFMA): out[b,c,i] = bias[c] + 0.5 * sum_h (1/l_i^h) * sum_j e~_ij z[j,c]
//   e~ = exp2( lrelu(d~_i + s~_j) - m~_i ),  scores pre-scaled by log2(e),
//   m~_i = lrelu(d~_i + max_j s~_j)  (lrelu monotone), l_i = sum_j e~  (in-reg).
// Block: 256 thr = 4 waves; wave w owns 16 rows i = ib + w*16 + (lane&15).
// A-frag (alpha) generated in-register; B-frag (zT) read from global (L2/L3).
// -----------------------------------------------------------------------------
__global__ __launch_bounds__(256)
void attn_kernel(const ushort* __restrict__ zt, const float* __restrict__ ssrc,
                 const float* __restrict__ sdst, const float* __restrict__ bias,
                 float* __restrict__ out)
{
    const int ib   = blockIdx.x * 64;
    const int b    = blockIdx.y;
    const int tid  = threadIdx.x;
    const int w    = tid >> 6;
    const int lane = tid & 63;
    const int lrow = lane & 15;      // A-row / B-col / D-col
    const int lq   = lane >> 4;      // quarter
    const int i_arow = ib + w * 16 + lrow;

    __shared__ float ssj[N_];

    f32x4 acc[2][8];
#pragma unroll
    for (int h = 0; h < 2; ++h)
#pragma unroll
        for (int ct = 0; ct < 8; ++ct)
#pragma unroll
            for (int r = 0; r < 4; ++r) acc[h][ct][r] = 0.f;

    float inv_l[2];

#pragma unroll
    for (int h = 0; h < 2; ++h) {
        const size_t bh = (size_t)(b * 2 + h);
        __syncthreads();
        for (int t = tid; t < N_; t += 256) ssj[t] = ssrc[bh * N_ + t] * L2E_;
        __syncthreads();

        // global max over s~ (all lanes redundant, cheap)
        float smax = -1e30f;
#pragma unroll
        for (int k = 0; k < 16; ++k) smax = fmaxf(smax, ssj[lane + k * 64]);
#pragma unroll
        for (int m = 1; m < 64; m <<= 1) smax = fmaxf(smax, __shfl_xor(smax, m, 64));

        const float dt = sdst[bh * N_ + i_arow] * L2E_;
        const float vm = dt + smax;
        const float mt = fmaxf(vm, 0.2f * vm);     // exact row max (monotone lrelu)

        float lsum = 0.f;
        const ushort* zbase = zt + bh * (size_t)(C_ * N_) + (size_t)lrow * N_ + lq * 8;

        for (int j0 = 0; j0 < N_; j0 += 32) {
            float4 s0 = *(const float4*)&ssj[j0 + lq * 8];
            float4 s1 = *(const float4*)&ssj[j0 + lq * 8 + 4];
            float e[8];
            {
                float sv[8] = {s0.x, s0.y, s0.z, s0.w, s1.x, s1.y, s1.z, s1.w};
#pragma unroll
                for (int r = 0; r < 8; ++r) {
                    float v = dt + sv[r];
                    float lr = fmaxf(v, 0.2f * v);
                    e[r] = exp2f(lr - mt);
                }
            }
            lsum += ((e[0] + e[1]) + (e[2] + e[3])) + ((e[4] + e[5]) + (e[6] + e[7]));
            bf16x8 af;
#pragma unroll
            for (int r = 0; r < 8; ++r) af[r] = (short)f2bf(e[r]);
#pragma unroll
            for (int ct = 0; ct < 8; ++ct) {
                bf16x8 bf = *(const bf16x8*)(zbase + (size_t)ct * 16 * N_ + j0);
                acc[h][ct] = __builtin_amdgcn_mfma_f32_16x16x32_bf16(af, bf, acc[h][ct], 0, 0, 0);
            }
        }
        lsum += __shfl_xor(lsum, 16, 64);
        lsum += __shfl_xor(lsum, 32, 64);
        inv_l[h] = 1.f / lsum;     // per-row (lrow) total, all lanes valid
    }

    // epilogue: head mean + bias; D row (lq*4+r) needs inv_l of that row
    float w0[4], w1[4];
#pragma unroll
    for (int r = 0; r < 4; ++r) {
        int src = lq * 4 + r;
        w0[r] = 0.5f * __shfl(inv_l[0], src, 64);
        w1[r] = 0.5f * __shfl(inv_l[1], src, 64);
    }
#pragma unroll
    for (int ct = 0; ct < 8; ++ct) {
        int c = ct * 16 + lrow;
        float bv = bias[c];
        float4 o;
        o.x = acc[0][ct][0] * w0[0] + acc[1][ct][0] * w1[0] + bv;
        o.y = acc[0][ct][1] * w0[1] + acc[1][ct][1] * w1[1] + bv;
        o.z = acc[0][ct][2] * w0[2] + acc[1][ct][2] * w1[2] + bv;
        o.w = acc[0][ct][3] * w0[3] + acc[1][ct][3] * w1[3] + bv;
        *(float4*)&out[((size_t)b * C_ + c) * N_ + ib + w * 16 + lq * 4] = o;
    }
}

extern "C" void kernel_launch(void* const* d_in, const int* in_sizes, int n_in,
                              void* d_out, int out_size, void* d_ws, size_t ws_size,
                              hipStream_t stream) {
    const float* x       = (const float*)d_in[0];
    const float* W       = (const float*)d_in[1];
    const float* att_src = (const float*)d_in[2];
    const float* att_dst = (const float*)d_in[3];
    const float* bias    = (const float*)d_in[4];
    float* out = (float*)d_out;

    // workspace: zT bf16 [B*H][C][N] (16.8 MB) | ssrc fp32 | sdst fp32
    ushort* zt  = (ushort*)d_ws;
    float* ssrc = (float*)(zt + (size_t)B_ * H_ * C_ * N_);
    float* sdst = ssrc + (size_t)B_ * H_ * N_;

    proj_kernel<<<dim3(N_ / 64, B_ * H_), 256, 0, stream>>>(
        x, W, att_src, att_dst, zt, ssrc, sdst);
    attn_kernel<<<dim3(N_ / 64, B_), 256, 0, stream>>>(
        zt, ssrc, sdst, bias, out);
}

// Round 4
// 200.573 us; speedup vs baseline: 4.6480x; 1.0894x over previous
//
#include <hip/hip_runtime.h>
#include <hip/hip_bf16.h>
#include <math.h>

constexpr int B_ = 32, S_ = 128, N_ = 1024, H_ = 2, C_ = 128;
#define L2E_ 1.44269504088896340736f

typedef short  bf16x8 __attribute__((ext_vector_type(8)));
typedef float  f32x4  __attribute__((ext_vector_type(4)));
typedef ushort u16x8  __attribute__((ext_vector_type(8)));

__device__ __forceinline__ ushort f2bf(float f) {
    __hip_bfloat16 h = __float2bfloat16(f);
    return __builtin_bit_cast(ushort, h);
}
__device__ __forceinline__ float bfhi(ushort u) {
    return __builtin_bit_cast(float, (uint)u << 16);
}

// -----------------------------------------------------------------------------
// Kernel 0 (prep): x [B,S,N] f32 -> xth/xtl [B,N,S] bf16 hi/lo (LDS transpose)
//                  W [H,S,C] f32 -> wth/wtl [H,C,S] bf16 hi/lo
// grid.x: 0..511 = x tiles (b = bx>>4, ntile = bx&15); 512..513 = W (h = bx-512)
// -----------------------------------------------------------------------------
__global__ __launch_bounds__(256)
void prep_kernel(const float* __restrict__ x, const float* __restrict__ W,
                 ushort* __restrict__ xth, ushort* __restrict__ xtl,
                 ushort* __restrict__ wth, ushort* __restrict__ wtl)
{
    __shared__ float sm[128 * 129];
    const int tid = threadIdx.x;
    const int bx = blockIdx.x;
    if (bx < 512) {
        const int b = bx >> 4, nb = (bx & 15) * 64;
        const float* xb = x + (size_t)b * S_ * N_;
#pragma unroll
        for (int it = 0; it < 32; ++it) {
            int e = it * 256 + tid;
            int s = e >> 6, n = e & 63;
            sm[s * 65 + n] = xb[(size_t)s * N_ + nb + n];
        }
        __syncthreads();
        const int n = tid >> 2, sc = (tid & 3) * 32;
        const size_t rowb = ((size_t)b * N_ + nb + n) * S_ + sc;
#pragma unroll
        for (int g = 0; g < 4; ++g) {
            u16x8 vh, vl;
#pragma unroll
            for (int e = 0; e < 8; ++e) {
                float v = sm[(sc + g * 8 + e) * 65 + n];
                ushort hh = f2bf(v);
                vh[e] = hh;
                vl[e] = f2bf(v - bfhi(hh));
            }
            *(u16x8*)&xth[rowb + g * 8] = vh;
            *(u16x8*)&xtl[rowb + g * 8] = vl;
        }
    } else {
        const int h = bx - 512;
        const float* Wh = W + (size_t)h * S_ * C_;
#pragma unroll
        for (int it = 0; it < 64; ++it) {
            int e = it * 256 + tid;
            int s = e >> 7, c = e & 127;
            sm[s * 129 + c] = Wh[s * C_ + c];
        }
        __syncthreads();
        const int c = tid >> 1, sh = (tid & 1) * 64;
        const size_t rowb = ((size_t)h * C_ + c) * S_ + sh;
#pragma unroll
        for (int g = 0; g < 8; ++g) {
            u16x8 vh, vl;
#pragma unroll
            for (int e = 0; e < 8; ++e) {
                float v = sm[(sh + g * 8 + e) * 129 + c];
                ushort hh = f2bf(v);
                vh[e] = hh;
                vl[e] = f2bf(v - bfhi(hh));
            }
            *(u16x8*)&wth[rowb + g * 8] = vh;
            *(u16x8*)&wtl[rowb + g * 8] = vl;
        }
    }
}

// -----------------------------------------------------------------------------
// Kernel 1 (proj, MFMA split-bf16): z = xt @ W  (3 passes: hh, hl, lh)
//   writes zt[bh][c][n] bf16 + exact fp32 scores ssrc/sdst.
// grid (N/64, B*H); 4 waves; wave w: rows nb+w*16..+15, all 128 c.
// -----------------------------------------------------------------------------
__global__ __launch_bounds__(256, 2)
void proj_kernel(const ushort* __restrict__ xth, const ushort* __restrict__ xtl,
                 const ushort* __restrict__ wth, const ushort* __restrict__ wtl,
                 const float* __restrict__ att_src, const float* __restrict__ att_dst,
                 ushort* __restrict__ zt, float* __restrict__ ssrc,
                 float* __restrict__ sdst)
{
    const int nb = blockIdx.x * 64;
    const int bh = blockIdx.y;
    const int b = bh >> 1, h = bh & 1;
    const int w = threadIdx.x >> 6, lane = threadIdx.x & 63;
    const int lrow = lane & 15, lq = lane >> 4;

    f32x4 acc[8];
#pragma unroll
    for (int ct = 0; ct < 8; ++ct)
#pragma unroll
        for (int r = 0; r < 4; ++r) acc[ct][r] = 0.f;

    const size_t xrow = ((size_t)b * N_ + nb + w * 16 + lrow) * S_ + lq * 8;
    const size_t wbase = (size_t)h * C_ * S_ + (size_t)lrow * S_ + lq * 8;

#pragma unroll
    for (int kc = 0; kc < 4; ++kc) {
        bf16x8 ah = *(const bf16x8*)(xth + xrow + kc * 32);
        bf16x8 al = *(const bf16x8*)(xtl + xrow + kc * 32);
#pragma unroll
        for (int ct = 0; ct < 8; ++ct) {
            const size_t wo = wbase + (size_t)ct * 16 * S_ + kc * 32;
            bf16x8 bh8 = *(const bf16x8*)(wth + wo);
            bf16x8 bl8 = *(const bf16x8*)(wtl + wo);
            acc[ct] = __builtin_amdgcn_mfma_f32_16x16x32_bf16(ah, bh8, acc[ct], 0, 0, 0);
            acc[ct] = __builtin_amdgcn_mfma_f32_16x16x32_bf16(ah, bl8, acc[ct], 0, 0, 0);
            acc[ct] = __builtin_amdgcn_mfma_f32_16x16x32_bf16(al, bh8, acc[ct], 0, 0, 0);
        }
    }

    // scores: s[n] = sum_c z[n,c] * att[c]; lane holds cols c=ct*16+lrow, rows lq*4+r
    float asrc[8], adst[8];
#pragma unroll
    for (int ct = 0; ct < 8; ++ct) {
        asrc[ct] = att_src[h * C_ + ct * 16 + lrow];
        adst[ct] = att_dst[h * C_ + ct * 16 + lrow];
    }
#pragma unroll
    for (int r = 0; r < 4; ++r) {
        float ps = 0.f, pd = 0.f;
#pragma unroll
        for (int ct = 0; ct < 8; ++ct) {
            ps = fmaf(acc[ct][r], asrc[ct], ps);
            pd = fmaf(acc[ct][r], adst[ct], pd);
        }
#pragma unroll
        for (int msk = 8; msk >= 1; msk >>= 1) {
            ps += __shfl_xor(ps, msk, 64);
            pd += __shfl_xor(pd, msk, 64);
        }
        if (lrow == 0) {
            ssrc[(size_t)bh * N_ + nb + w * 16 + lq * 4 + r] = ps;
            sdst[(size_t)bh * N_ + nb + w * 16 + lq * 4 + r] = pd;
        }
    }

    // zt[bh][c][n] bf16
#pragma unroll
    for (int ct = 0; ct < 8; ++ct) {
        ushort4 v;
        v.x = f2bf(acc[ct][0]); v.y = f2bf(acc[ct][1]);
        v.z = f2bf(acc[ct][2]); v.w = f2bf(acc[ct][3]);
        *(ushort4*)&zt[((size_t)bh * C_ + ct * 16 + lrow) * N_ + nb + w * 16 + lq * 4] = v;
    }
}

// -----------------------------------------------------------------------------
// Kernel 2 (lsum): per row i of head bh: q = mt + log2(sum_j 2^(lrelu~ - mt))
//   outputs ca = dt - q, cb = 0.2dt - q  (so alpha = 2^max(sv+ca, 0.2sv+cb))
// grid (4, 64): 256 rows per block, one thread per row.
// -----------------------------------------------------------------------------
__global__ __launch_bounds__(256)
void lsum_kernel(const float* __restrict__ ssrc, const float* __restrict__ sdst,
                 float* __restrict__ caA, float* __restrict__ cbA)
{
    const int bh = blockIdx.y, ib = blockIdx.x * 256;
    const int tid = threadIdx.x;
    __shared__ float sj[N_];
    __shared__ float red[4];

    float pm = -1e30f;
#pragma unroll
    for (int it = 0; it < 4; ++it) {
        int j = it * 256 + tid;
        float v = ssrc[(size_t)bh * N_ + j] * L2E_;
        sj[j] = v;
        pm = fmaxf(pm, v);
    }
#pragma unroll
    for (int msk = 1; msk < 64; msk <<= 1) pm = fmaxf(pm, __shfl_xor(pm, msk, 64));
    if ((tid & 63) == 0) red[tid >> 6] = pm;
    __syncthreads();
    const float smax = fmaxf(fmaxf(red[0], red[1]), fmaxf(red[2], red[3]));

    const float dt = sdst[(size_t)bh * N_ + ib + tid] * L2E_;
    const float vm = dt + smax;
    const float mt = fmaxf(vm, 0.2f * vm);
    const float c1 = dt - mt, c2 = 0.2f * dt - mt;

    float l0 = 0.f, l1 = 0.f, l2 = 0.f, l3 = 0.f;
    for (int j = 0; j < N_; j += 4) {
        float4 s4 = *(const float4*)&sj[j];
        l0 += exp2f(fmaxf(s4.x + c1, fmaf(0.2f, s4.x, c2)));
        l1 += exp2f(fmaxf(s4.y + c1, fmaf(0.2f, s4.y, c2)));
        l2 += exp2f(fmaxf(s4.z + c1, fmaf(0.2f, s4.z, c2)));
        l3 += exp2f(fmaxf(s4.w + c1, fmaf(0.2f, s4.w, c2)));
    }
    const float q = log2f((l0 + l1) + (l2 + l3));
    caA[(size_t)bh * N_ + ib + tid] = c1 - q;
    cbA[(size_t)bh * N_ + ib + tid] = c2 - q;
}

// -----------------------------------------------------------------------------
// Kernel 3 (attn): out[b,c,i] = bias[c] + 0.5*sum_h sum_j alpha~ * z[h,j,c]
//   alpha~ pre-normalized. 256 blocks (1/CU), 4 waves: (rowgroup rg, head h).
//   z chunks (64 j x 128 c x 2 heads) staged via global_load_lds, XOR-swizzled,
//   double-buffered. Heads combined through LDS at epilogue.
// -----------------------------------------------------------------------------
__device__ __forceinline__ void stage_chunk(const ushort* __restrict__ zt, uint* zstage,
                                            int b, int w, int lane, int buf, int j0)
{
#pragma unroll
    for (int it = 0; it < 8; ++it) {
        int id = (w * 8 + it) * 64 + lane;
        int hh = id >> 10, c = (id >> 3) & 127, jq = id & 7;
        const uint* src = (const uint*)(zt + (((size_t)(b * 2 + hh) * C_ + c) * N_)
                                       + j0 + ((jq ^ (c & 7)) << 3));
        __builtin_amdgcn_global_load_lds(
            (const __attribute__((address_space(1))) uint*)src,
            (__attribute__((address_space(3))) uint*)&zstage[buf * 8192 + (w * 8 + it) * 256],
            16, 0, 0);
    }
}

__global__ __launch_bounds__(256, 1)
void attn_kernel(const ushort* __restrict__ zt, const float* __restrict__ ssrc,
                 const float* __restrict__ caA, const float* __restrict__ cbA,
                 const float* __restrict__ bias, float* __restrict__ out)
{
    const int bx = blockIdx.x;      // 0..7 (128-row block)
    const int b  = blockIdx.y;
    const int tid = threadIdx.x;
    const int w = tid >> 6, lane = tid & 63;
    const int rg = w >> 1, h = w & 1;
    const int lrow = lane & 15, lq = lane >> 4;
    const int rowbase = bx * 128 + rg * 64;
    const size_t bh = (size_t)b * 2 + h;

    __shared__ uint  zstage[16384];     // 64 KB: [buf][hh][c][8 x 16B]
    __shared__ float ssjl[2][N_];       // 8 KB

    float ca[4], cb[4], bv[8];
#pragma unroll
    for (int t = 0; t < 4; ++t) {
        ca[t] = caA[bh * N_ + rowbase + t * 16 + lrow];
        cb[t] = cbA[bh * N_ + rowbase + t * 16 + lrow];
    }
#pragma unroll
    for (int ct = 0; ct < 8; ++ct) bv[ct] = bias[ct * 16 + lrow];

#pragma unroll
    for (int it = 0; it < 8; ++it) {
        int e = it * 256 + tid;
        int hh = e >> 10, j = e & 1023;
        ssjl[hh][j] = ssrc[((size_t)b * 2 + hh) * N_ + j] * L2E_;
    }

    stage_chunk(zt, zstage, b, w, lane, 0, 0);
    __syncthreads();

    f32x4 acc[4][8];
#pragma unroll
    for (int t = 0; t < 4; ++t)
#pragma unroll
        for (int ct = 0; ct < 8; ++ct)
#pragma unroll
            for (int r = 0; r < 4; ++r) acc[t][ct][r] = 0.f;

    int buf = 0;
    for (int jc = 0; jc < 16; ++jc) {
        if (jc < 15) stage_chunk(zt, zstage, b, w, lane, buf ^ 1, (jc + 1) * 64);
#pragma unroll
        for (int ks = 0; ks < 2; ++ks) {
            const int j32 = jc * 64 + ks * 32;
            bf16x8 bf[8];
#pragma unroll
            for (int ct = 0; ct < 8; ++ct) {
                int c = ct * 16 + lrow;
                int off = buf * 32768 + h * 16384 + c * 128 + ((((ks * 4) + lq) ^ (c & 7)) << 4);
                bf[ct] = *(const bf16x8*)((const char*)zstage + off);
            }
            float4 s0 = *(const float4*)&ssjl[h][j32 + lq * 8];
            float4 s1 = *(const float4*)&ssjl[h][j32 + lq * 8 + 4];
            float sv[8] = {s0.x, s0.y, s0.z, s0.w, s1.x, s1.y, s1.z, s1.w};
#pragma unroll
            for (int t = 0; t < 4; ++t) {
                bf16x8 af;
#pragma unroll
                for (int r = 0; r < 8; ++r) {
                    float e1 = fmaxf(sv[r] + ca[t], fmaf(0.2f, sv[r], cb[t]));
                    af[r] = (short)f2bf(exp2f(e1));
                }
#pragma unroll
                for (int ct = 0; ct < 8; ++ct)
                    acc[t][ct] = __builtin_amdgcn_mfma_f32_16x16x32_bf16(af, bf[ct], acc[t][ct], 0, 0, 0);
            }
        }
        __syncthreads();
        buf ^= 1;
    }

    // epilogue: combine heads via LDS (reuse zstage), mean + bias, store
    float* exch = (float*)zstage;   // [rg][t][ct][lrow][16]
    if (h == 1) {
#pragma unroll
        for (int t = 0; t < 4; ++t)
#pragma unroll
            for (int ct = 0; ct < 8; ++ct) {
                int idx = ((((rg * 4 + t) * 8 + ct) * 16 + lrow) * 16) + lq * 4;
                *(float4*)&exch[idx] = *(float4*)&acc[t][ct];
            }
    }
    __syncthreads();
    if (h == 0) {
#pragma unroll
        for (int t = 0; t < 4; ++t)
#pragma unroll
            for (int ct = 0; ct < 8; ++ct) {
                int idx = ((((rg * 4 + t) * 8 + ct) * 16 + lrow) * 16) + lq * 4;
                float4 v = *(const float4*)&exch[idx];
                int c = ct * 16 + lrow;
                float4 o;
                o.x = 0.5f * (acc[t][ct][0] + v.x) + bv[ct];
                o.y = 0.5f * (acc[t][ct][1] + v.y) + bv[ct];
                o.z = 0.5f * (acc[t][ct][2] + v.z) + bv[ct];
                o.w = 0.5f * (acc[t][ct][3] + v.w) + bv[ct];
                *(float4*)&out[((size_t)b * C_ + c) * N_ + rowbase + t * 16 + lq * 4] = o;
            }
    }
}

extern "C" void kernel_launch(void* const* d_in, const int* in_sizes, int n_in,
                              void* d_out, int out_size, void* d_ws, size_t ws_size,
                              hipStream_t stream) {
    const float* x       = (const float*)d_in[0];
    const float* W       = (const float*)d_in[1];
    const float* att_src = (const float*)d_in[2];
    const float* att_dst = (const float*)d_in[3];
    const float* bias    = (const float*)d_in[4];
    float* out = (float*)d_out;

    ushort* xth = (ushort*)d_ws;
    ushort* xtl = xth + (size_t)B_ * N_ * S_;
    ushort* wth = xtl + (size_t)B_ * N_ * S_;
    ushort* wtl = wth + (size_t)H_ * C_ * S_;
    ushort* zt  = wtl + (size_t)H_ * C_ * S_;
    float* ssrc = (float*)(zt + (size_t)B_ * H_ * C_ * N_);
    float* sdst = ssrc + (size_t)B_ * H_ * N_;
    float* caA  = sdst + (size_t)B_ * H_ * N_;
    float* cbA  = caA + (size_t)B_ * H_ * N_;

    prep_kernel<<<dim3(514), 256, 0, stream>>>(x, W, xth, xtl, wth, wtl);
    proj_kernel<<<dim3(N_ / 64, B_ * H_), 256, 0, stream>>>(
        xth, xtl, wth, wtl, att_src, att_dst, zt, ssrc, sdst);
    lsum_kernel<<<dim3(4, B_ * H_), 256, 0, stream>>>(ssrc, sdst, caA, cbA);
    attn_kernel<<<dim3(8, B_), 256, 0, stream>>>(zt, ssrc, caA, cbA, bias, out);
}

// Round 5
// 171.894 us; speedup vs baseline: 5.4234x; 1.1668x over previous
//
#include <hip/hip_runtime.h>
#include <hip/hip_bf16.h>
#include <math.h>

constexpr int B_ = 32, S_ = 128, N_ = 1024, H_ = 2, C_ = 128;
#define L2E_ 1.44269504088896340736f

typedef short  bf16x8 __attribute__((ext_vector_type(8)));
typedef float  f32x4  __attribute__((ext_vector_type(4)));
typedef ushort u16x8  __attribute__((ext_vector_type(8)));

__device__ __forceinline__ ushort f2bf(float f) {
    __hip_bfloat16 h = __float2bfloat16(f);
    return __builtin_bit_cast(ushort, h);
}
__device__ __forceinline__ float bfhi(ushort u) {
    return __builtin_bit_cast(float, (uint)u << 16);
}

// -----------------------------------------------------------------------------
// Kernel 0 (wprep): W [H,S,C] f32 -> wth/wtl [H,C,S] bf16 hi/lo. grid(2).
// -----------------------------------------------------------------------------
__global__ __launch_bounds__(512)
void wprep_kernel(const float* __restrict__ W,
                  ushort* __restrict__ wth, ushort* __restrict__ wtl)
{
    __shared__ float sm[128 * 129];
    const int h = blockIdx.x, tid = threadIdx.x;
    const float* Wh = W + (size_t)h * S_ * C_;
#pragma unroll
    for (int it = 0; it < 32; ++it) {
        int e = it * 512 + tid;
        int s = e >> 7, c = e & 127;
        sm[s * 129 + c] = Wh[e];
    }
    __syncthreads();
    const int c = tid >> 2, sg = (tid & 3) * 32;
    const size_t rowb = ((size_t)h * C_ + c) * S_ + sg;
#pragma unroll
    for (int g = 0; g < 4; ++g) {
        u16x8 vh, vl;
#pragma unroll
        for (int e = 0; e < 8; ++e) {
            float v = sm[(sg + g * 8 + e) * 129 + c];
            ushort hh = f2bf(v);
            vh[e] = hh;
            vl[e] = f2bf(v - bfhi(hh));
        }
        *(u16x8*)&wth[rowb + g * 8] = vh;
        *(u16x8*)&wtl[rowb + g * 8] = vl;
    }
}

// -----------------------------------------------------------------------------
// Kernel 1 (proj): z = x^T W via MFMA split-bf16 (hh+hl+lh), A-frags gathered
// straight from x's native [s][n] layout (16 consecutive-n lanes = 1 cache line),
// converted to hi/lo bf16 in-register. Writes zt[bh][c][n] bf16 + exact scores.
// grid (8, 32): block = 128 n x 128 c x 2 heads. 8 waves = wn(4) x wh(2).
// -----------------------------------------------------------------------------
__global__ __launch_bounds__(512, 2)
void proj_kernel(const float* __restrict__ x,
                 const ushort* __restrict__ wth, const ushort* __restrict__ wtl,
                 const float* __restrict__ att_src, const float* __restrict__ att_dst,
                 ushort* __restrict__ zt, float* __restrict__ ssrc,
                 float* __restrict__ sdst)
{
    const int nb = blockIdx.x * 128;
    const int b  = blockIdx.y;
    const int w = threadIdx.x >> 6, lane = threadIdx.x & 63;
    const int wn = w >> 1, wh = w & 1;
    const int lrow = lane & 15, lq = lane >> 4;
    const size_t bh = (size_t)(b * 2 + wh);

    f32x4 acc[2][8];
#pragma unroll
    for (int tt = 0; tt < 2; ++tt)
#pragma unroll
        for (int ct = 0; ct < 8; ++ct)
#pragma unroll
            for (int r = 0; r < 4; ++r) acc[tt][ct][r] = 0.f;

    const float* xp0 = x + (size_t)b * S_ * N_ + nb + wn * 32 + lrow;
    const size_t wbase = (size_t)wh * C_ * S_ + (size_t)lrow * S_ + lq * 8;

#pragma unroll
    for (int kc = 0; kc < 4; ++kc) {
        bf16x8 ah[2], al[2];
#pragma unroll
        for (int tt = 0; tt < 2; ++tt) {
            const float* xp = xp0 + tt * 16 + (size_t)(kc * 32 + lq * 8) * N_;
#pragma unroll
            for (int e = 0; e < 8; ++e) {
                float v = xp[(size_t)e * N_];
                ushort hi = f2bf(v);
                ah[tt][e] = (short)hi;
                al[tt][e] = (short)f2bf(v - bfhi(hi));
            }
        }
#pragma unroll
        for (int ct = 0; ct < 8; ++ct) {
            const size_t wo = wbase + (size_t)ct * 16 * S_ + kc * 32;
            bf16x8 bhv = *(const bf16x8*)(wth + wo);
            bf16x8 blv = *(const bf16x8*)(wtl + wo);
#pragma unroll
            for (int tt = 0; tt < 2; ++tt) {
                acc[tt][ct] = __builtin_amdgcn_mfma_f32_16x16x32_bf16(ah[tt], bhv, acc[tt][ct], 0, 0, 0);
                acc[tt][ct] = __builtin_amdgcn_mfma_f32_16x16x32_bf16(ah[tt], blv, acc[tt][ct], 0, 0, 0);
                acc[tt][ct] = __builtin_amdgcn_mfma_f32_16x16x32_bf16(al[tt], bhv, acc[tt][ct], 0, 0, 0);
            }
        }
    }

    // scores (fp32 exact): s[n] = sum_c z[n,c]*att[c]; reduce over lrow
    float asrc[8], adst[8];
#pragma unroll
    for (int ct = 0; ct < 8; ++ct) {
        asrc[ct] = att_src[wh * C_ + ct * 16 + lrow];
        adst[ct] = att_dst[wh * C_ + ct * 16 + lrow];
    }
#pragma unroll
    for (int tt = 0; tt < 2; ++tt)
#pragma unroll
        for (int r = 0; r < 4; ++r) {
            float ps = 0.f, pd = 0.f;
#pragma unroll
            for (int ct = 0; ct < 8; ++ct) {
                ps = fmaf(acc[tt][ct][r], asrc[ct], ps);
                pd = fmaf(acc[tt][ct][r], adst[ct], pd);
            }
#pragma unroll
            for (int msk = 8; msk >= 1; msk >>= 1) {
                ps += __shfl_xor(ps, msk, 64);
                pd += __shfl_xor(pd, msk, 64);
            }
            if (lrow == 0) {
                int n = nb + wn * 32 + tt * 16 + lq * 4 + r;
                ssrc[bh * N_ + n] = ps;
                sdst[bh * N_ + n] = pd;
            }
        }

    // zt[bh][c][n]
#pragma unroll
    for (int tt = 0; tt < 2; ++tt)
#pragma unroll
        for (int ct = 0; ct < 8; ++ct) {
            ushort4 v;
            v.x = f2bf(acc[tt][ct][0]); v.y = f2bf(acc[tt][ct][1]);
            v.z = f2bf(acc[tt][ct][2]); v.w = f2bf(acc[tt][ct][3]);
            *(ushort4*)&zt[(bh * C_ + ct * 16 + lrow) * N_ + nb + wn * 32 + tt * 16 + lq * 4] = v;
        }
}

// -----------------------------------------------------------------------------
// Kernel 2 (lsum): e-domain constants. e1=2^sv, e2=2^(0.2sv) per (bh,j);
// per row i: L = sum_j sel(e1_j>=Tr)?pA*e1:pB*e2; A=0.5pA/L, B=0.5pB/L, Tr=2^-dt.
// grid (4, 64), 256 thr, thread = one row.
// -----------------------------------------------------------------------------
__global__ __launch_bounds__(256)
void lsum_kernel(const float* __restrict__ ssrc, const float* __restrict__ sdst,
                 float* __restrict__ e1t, float* __restrict__ e2t,
                 float* __restrict__ Aar, float* __restrict__ Bar,
                 float* __restrict__ Trar)
{
    const int bh = blockIdx.y, ib = blockIdx.x * 256;
    const int tid = threadIdx.x;
    __shared__ float e1s[N_], e2s[N_];

#pragma unroll
    for (int it = 0; it < 4; ++it) {
        int j = it * 256 + tid;
        float sv = ssrc[(size_t)bh * N_ + j] * L2E_;
        e1s[j] = exp2f(sv);
        e2s[j] = exp2f(0.2f * sv);
    }
    __syncthreads();

    const int i = ib + tid;
    e1t[(size_t)bh * N_ + i] = e1s[i];
    e2t[(size_t)bh * N_ + i] = e2s[i];

    const float dt = sdst[(size_t)bh * N_ + i] * L2E_;
    const float pA = exp2f(dt), pB = exp2f(0.2f * dt), Tr = exp2f(-dt);

    float l0 = 0.f, l1 = 0.f, l2 = 0.f, l3 = 0.f;
    for (int j = 0; j < N_; j += 4) {
        float a0 = e1s[j],     a1 = e1s[j + 1], a2 = e1s[j + 2], a3 = e1s[j + 3];
        float b0 = e2s[j],     b1 = e2s[j + 1], b2 = e2s[j + 2], b3 = e2s[j + 3];
        l0 += (a0 >= Tr) ? pA * a0 : pB * b0;
        l1 += (a1 >= Tr) ? pA * a1 : pB * b1;
        l2 += (a2 >= Tr) ? pA * a2 : pB * b2;
        l3 += (a3 >= Tr) ? pA * a3 : pB * b3;
    }
    const float inv = 0.5f / ((l0 + l1) + (l2 + l3));   // fold head-mean 0.5
    Aar[(size_t)bh * N_ + i]  = pA * inv;
    Bar[(size_t)bh * N_ + i]  = pB * inv;
    Trar[(size_t)bh * N_ + i] = Tr;
}

// -----------------------------------------------------------------------------
// Kernel 3 (attn): out[b,c,i] = bias[c] + sum_h sum_j alpha~ * z[h,j,c]
// alpha~ = sel(e1_j>=Tr_i) ? A_i*e1_j : B_i*e2_j  (pre-normalized, 0.5 folded).
// grid 256 1-D XCD-packed; 512 thr = 8 waves (rg x h x js); per wave 64 rows x
// 128 c x its 32-j half of each 64-j chunk. z double-buffered via gl_lds+swizzle.
// -----------------------------------------------------------------------------
__device__ __forceinline__ void stage_chunk512(const ushort* __restrict__ zt,
                                               uint* zstage, int b, int w,
                                               int lane, int buf, int j0)
{
#pragma unroll
    for (int it = 0; it < 4; ++it) {
        int id = (w * 4 + it) * 64 + lane;            // 0..2047
        int hh = id >> 10, c = (id >> 3) & 127, jq = id & 7;
        const uint* src = (const uint*)(zt + (((size_t)(b * 2 + hh) * C_ + c) * N_)
                                       + j0 + ((jq ^ (c & 7)) << 3));
        __builtin_amdgcn_global_load_lds(
            (const __attribute__((address_space(1))) uint*)src,
            (__attribute__((address_space(3))) uint*)&zstage[buf * 8192 + (w * 4 + it) * 256],
            16, 0, 0);
    }
}

__global__ __launch_bounds__(512, 2)
void attn_kernel(const ushort* __restrict__ zt,
                 const float* __restrict__ e1t, const float* __restrict__ e2t,
                 const float* __restrict__ Aar, const float* __restrict__ Bar,
                 const float* __restrict__ Trar, const float* __restrict__ bias,
                 float* __restrict__ out)
{
    // XCD-packed decode: all 8 row-blocks of a batch land on one XCD
    const int id0 = blockIdx.x;
    const int xcd = id0 & 7, k = id0 >> 3;
    const int b = xcd * 4 + (k >> 3), bx = k & 7;

    const int tid = threadIdx.x;
    const int w = tid >> 6, lane = tid & 63;
    const int rg = w >> 2, h = (w >> 1) & 1, js = w & 1;
    const int lrow = lane & 15, lq = lane >> 4;
    const int rowbase = bx * 128 + rg * 64;
    const size_t bh = (size_t)(b * 2 + h);

    __shared__ char pool[128 * 132 * 4];      // exch 67.5 KB; zstage 64 KB overlay
    __shared__ float e1s[2][N_], e2s[2][N_];  // 16 KB
    uint* zstage = (uint*)pool;
    float* exch  = (float*)pool;

    float A4[4], B4[4], T4[4];
#pragma unroll
    for (int t = 0; t < 4; ++t) {
        int i = rowbase + t * 16 + lrow;
        A4[t] = Aar[bh * N_ + i];
        B4[t] = Bar[bh * N_ + i];
        T4[t] = Trar[bh * N_ + i];
    }
#pragma unroll
    for (int it = 0; it < 4; ++it) {
        int e = it * 512 + tid;
        int hh = e >> 10, j = e & 1023;
        e1s[hh][j] = e1t[((size_t)b * 2 + hh) * N_ + j];
        e2s[hh][j] = e2t[((size_t)b * 2 + hh) * N_ + j];
    }
    stage_chunk512(zt, zstage, b, w, lane, 0, 0);
    __syncthreads();

    f32x4 acc[4][8];
#pragma unroll
    for (int t = 0; t < 4; ++t)
#pragma unroll
        for (int ct = 0; ct < 8; ++ct)
#pragma unroll
            for (int r = 0; r < 4; ++r) acc[t][ct][r] = 0.f;

    int buf = 0;
    for (int jc = 0; jc < 16; ++jc) {
        if (jc < 15) stage_chunk512(zt, zstage, b, w, lane, buf ^ 1, (jc + 1) * 64);
        const int j32 = jc * 64 + js * 32;

        float4 e1a = *(const float4*)&e1s[h][j32 + lq * 8];
        float4 e1b = *(const float4*)&e1s[h][j32 + lq * 8 + 4];
        float4 e2a = *(const float4*)&e2s[h][j32 + lq * 8];
        float4 e2b = *(const float4*)&e2s[h][j32 + lq * 8 + 4];
        float ev1[8] = {e1a.x, e1a.y, e1a.z, e1a.w, e1b.x, e1b.y, e1b.z, e1b.w};
        float ev2[8] = {e2a.x, e2a.y, e2a.z, e2a.w, e2b.x, e2b.y, e2b.z, e2b.w};

        bf16x8 bf[8];
#pragma unroll
        for (int ct = 0; ct < 8; ++ct) {
            int c = ct * 16 + lrow;
            int off = buf * 32768 + h * 16384 + c * 128 + ((((js * 4) + lq) ^ (c & 7)) << 4);
            bf[ct] = *(const bf16x8*)((const char*)zstage + off);
        }
#pragma unroll
        for (int t = 0; t < 4; ++t) {
            bf16x8 af;
#pragma unroll
            for (int r = 0; r < 8; ++r) {
                float al = (ev1[r] >= T4[t]) ? A4[t] * ev1[r] : B4[t] * ev2[r];
                af[r] = (short)f2bf(al);
            }
#pragma unroll
            for (int ct = 0; ct < 8; ++ct)
                acc[t][ct] = __builtin_amdgcn_mfma_f32_16x16x32_bf16(af, bf[ct], acc[t][ct], 0, 0, 0);
        }
        __syncthreads();
        buf ^= 1;
    }

    // epilogue: accumulate 4 wave-groups (h,js) into exch[c][132-padded i]
    const int grp = w & 3;
#pragma unroll 1
    for (int p = 0; p < 4; ++p) {
        if (grp == p) {
#pragma unroll
            for (int t = 0; t < 4; ++t)
#pragma unroll
                for (int ct = 0; ct < 8; ++ct) {
                    int c = ct * 16 + lrow;
                    int i = rg * 64 + t * 16 + lq * 4;
                    float* dst = &exch[c * 132 + i];
                    if (p == 0) {
                        *(float4*)dst = make_float4(acc[t][ct][0], acc[t][ct][1],
                                                    acc[t][ct][2], acc[t][ct][3]);
                    } else {
                        float4 v = *(const float4*)dst;
                        v.x += acc[t][ct][0]; v.y += acc[t][ct][1];
                        v.z += acc[t][ct][2]; v.w += acc[t][ct][3];
                        *(float4*)dst = v;
                    }
                }
        }
        __syncthreads();
    }

    // store: 32 lanes x float4 = 512 B contiguous runs per c-row
    const int cl = tid >> 5, il = (tid & 31) * 4;
#pragma unroll
    for (int it = 0; it < 8; ++it) {
        int c = it * 16 + cl;
        float bvv = bias[c];
        float4 v = *(const float4*)&exch[c * 132 + il];
        v.x += bvv; v.y += bvv; v.z += bvv; v.w += bvv;
        *(float4*)&out[((size_t)b * C_ + c) * N_ + bx * 128 + il] = v;
    }
}

extern "C" void kernel_launch(void* const* d_in, const int* in_sizes, int n_in,
                              void* d_out, int out_size, void* d_ws, size_t ws_size,
                              hipStream_t stream) {
    const float* x       = (const float*)d_in[0];
    const float* W       = (const float*)d_in[1];
    const float* att_src = (const float*)d_in[2];
    const float* att_dst = (const float*)d_in[3];
    const float* bias    = (const float*)d_in[4];
    float* out = (float*)d_out;

    ushort* wth = (ushort*)d_ws;                              // 2*128*128
    ushort* wtl = wth + (size_t)H_ * C_ * S_;
    ushort* zt  = wtl + (size_t)H_ * C_ * S_;                 // 64*128*1024
    float* ssrc = (float*)(zt + (size_t)B_ * H_ * C_ * N_);
    float* sdst = ssrc + (size_t)B_ * H_ * N_;
    float* e1t  = sdst + (size_t)B_ * H_ * N_;
    float* e2t  = e1t + (size_t)B_ * H_ * N_;
    float* Aar  = e2t + (size_t)B_ * H_ * N_;
    float* Bar  = Aar + (size_t)B_ * H_ * N_;
    float* Trar = Bar + (size_t)B_ * H_ * N_;

    wprep_kernel<<<dim3(2), 512, 0, stream>>>(W, wth, wtl);
    proj_kernel<<<dim3(8, 32), 512, 0, stream>>>(
        x, wth, wtl, att_src, att_dst, zt, ssrc, sdst);
    lsum_kernel<<<dim3(4, B_ * H_), 256, 0, stream>>>(
        ssrc, sdst, e1t, e2t, Aar, Bar, Trar);
    attn_kernel<<<dim3(256), 512, 0, stream>>>(
        zt, e1t, e2t, Aar, Bar, Trar, bias, out);
}